// Round 1
// baseline (1032.007 us; speedup 1.0000x reference)
//
#include <hip/hip_runtime.h>
#include <math.h>

#define NN 500000
#define NB 8192
#define GMAX 16
#define TILE_M 128

typedef _Float16 f16x8 __attribute__((ext_vector_type(8)));
typedef float f32x4 __attribute__((ext_vector_type(4)));

__device__ inline f16x8 zero8() {
    f16x8 v;
#pragma unroll
    for (int i = 0; i < 8; ++i) v[i] = (_Float16)0.f;
    return v;
}

// ---------------- weight prep: W^T as f16 ----------------
__global__ void prep_w(const float* __restrict__ nw1, const float* __restrict__ nw2,
                       const float* __restrict__ gw1, const float* __restrict__ gw2,
                       _Float16* __restrict__ wT1, _Float16* __restrict__ wT2,
                       _Float16* __restrict__ wTg, _Float16* __restrict__ g2h) {
    int k = blockIdx.x;   // 0..127 (input dim)
    int n = threadIdx.x;  // 0..127 (output dim)
    wT1[n * 128 + k] = (_Float16)nw1[k * 128 + n];
    wT2[n * 128 + k] = (_Float16)nw2[k * 128 + n];
    wTg[n * 128 + k] = (_Float16)gw1[k * 128 + n];
    if (k == 0) g2h[n] = (_Float16)gw2[n];
}

// ---------------- ques MLP (fp32) + zero P,s ----------------
__global__ void prep_q(const float* __restrict__ u, const float* __restrict__ qw1,
                       const float* __restrict__ qb1, const float* __restrict__ qw2,
                       const float* __restrict__ qb2, float* __restrict__ q,
                       float* __restrict__ P, float* __restrict__ s) {
    __shared__ float us[8][128];
    __shared__ float ts[8][132];
    int c = threadIdx.x;
    int b0 = blockIdx.x * 8;
#pragma unroll
    for (int j = 0; j < 8; ++j) us[j][c] = u[(size_t)(b0 + j) * 128 + c];
#pragma unroll
    for (int j = 0; j < 8; ++j) P[(size_t)(b0 + j) * 128 + c] = 0.f;
    if (c < 8) s[b0 + c] = 0.f;
    __syncthreads();
    float acc[8];
#pragma unroll
    for (int j = 0; j < 8; ++j) acc[j] = 0.f;
    for (int k = 0; k < 128; ++k) {
        float w = qw1[k * 128 + c];
#pragma unroll
        for (int j = 0; j < 8; ++j) acc[j] = fmaf(us[j][k], w, acc[j]);
    }
    float b1v = qb1[c];
#pragma unroll
    for (int j = 0; j < 8; ++j) ts[j][c] = fmaxf(acc[j] + b1v, 0.f);
    __syncthreads();
#pragma unroll
    for (int j = 0; j < 8; ++j) acc[j] = 0.f;
    for (int k = 0; k < 128; ++k) {
        float w = qw2[k * 128 + c];
#pragma unroll
        for (int j = 0; j < 8; ++j) acc[j] = fmaf(ts[j][k], w, acc[j]);
    }
    float b2v = qb2[c];
#pragma unroll
    for (int j = 0; j < 8; ++j) q[(size_t)(b0 + j) * 128 + c] = acc[j] + b2v;
}

// ---------------- fused node-MLP + gate + segment-weighted pooling ----------------
__launch_bounds__(512, 2)
__global__ void hg_kernel(const float* __restrict__ x, const int* __restrict__ batch,
                          const float* __restrict__ qglob,
                          const _Float16* __restrict__ wT1, const _Float16* __restrict__ wT2,
                          const _Float16* __restrict__ wTg, const _Float16* __restrict__ g2h,
                          const float* __restrict__ nb1, const float* __restrict__ nb2,
                          const float* __restrict__ gb1, const float* __restrict__ gb2,
                          float* __restrict__ P, float* __restrict__ s) {
    __shared__ __align__(16) _Float16 tbuf[TILE_M][136];  // 34.8 KB, reused t1 -> gin -> t2
    __shared__ float qs[GMAX][132];
    __shared__ float Pacc[GMAX][132];
    __shared__ float sacc[GMAX];
    __shared__ int batch_t[TILE_M];
    __shared__ int maxrel_sh;

    const int tid  = threadIdx.x;
    const int wave = tid >> 6;
    const int lane = tid & 63;
    const int lrow = lane & 15;
    const int quad = lane >> 4;
    const int wr   = wave >> 1;  // 0..3  (32-row group)
    const int wc   = wave & 1;   // 0..1  (64-col group)
    const int row0 = blockIdx.x * TILE_M;
    const int rbase = wr * 32;

    if (tid < TILE_M) {
        int gr = row0 + tid;
        batch_t[tid] = (gr < NN) ? batch[gr] : batch[NN - 1];
    }
    if (tid == 0) maxrel_sh = 0;
    __syncthreads();
    const int b_lo = batch_t[0];
    if (tid < TILE_M) atomicMax(&maxrel_sh, batch_t[tid] - b_lo);
    for (int idx = tid; idx < GMAX * 132; idx += 512) ((float*)Pacc)[idx] = 0.f;
    if (tid < GMAX) sacc[tid] = 0.f;
    __syncthreads();
    const int maxrel = maxrel_sh;
    const int gcnt = min(maxrel + 1, GMAX);
    for (int idx = tid; idx < gcnt * 128; idx += 512) {
        int g = idx >> 7, c = idx & 127;
        qs[g][c] = qglob[(size_t)(b_lo + g) * 128 + c];
    }
    __syncthreads();

    f32x4 acc[2][4];
    const f32x4 fz = {0.f, 0.f, 0.f, 0.f};
#pragma unroll
    for (int mi = 0; mi < 2; ++mi)
#pragma unroll
        for (int ci = 0; ci < 4; ++ci) acc[mi][ci] = fz;

    // ===== M1: t1 = relu(x @ w1 + b1) -> tbuf =====
#pragma unroll
    for (int ki = 0; ki < 4; ++ki) {
        const int k = ki * 32 + quad * 8;
        f16x8 a[2];
#pragma unroll
        for (int mi = 0; mi < 2; ++mi) {
            int r = row0 + rbase + mi * 16 + lrow;
            if (r < NN) {
                const float4* xp = (const float4*)(x + (size_t)r * 128 + k);
                float4 x0 = xp[0], x1 = xp[1];
                f16x8 af;
                af[0] = (_Float16)x0.x; af[1] = (_Float16)x0.y;
                af[2] = (_Float16)x0.z; af[3] = (_Float16)x0.w;
                af[4] = (_Float16)x1.x; af[5] = (_Float16)x1.y;
                af[6] = (_Float16)x1.z; af[7] = (_Float16)x1.w;
                a[mi] = af;
            } else {
                a[mi] = zero8();
            }
        }
        f16x8 b[4];
#pragma unroll
        for (int ci = 0; ci < 4; ++ci)
            b[ci] = *(const f16x8*)(wT1 + (size_t)(wc * 64 + ci * 16 + lrow) * 128 + k);
#pragma unroll
        for (int mi = 0; mi < 2; ++mi)
#pragma unroll
            for (int ci = 0; ci < 4; ++ci)
                acc[mi][ci] = __builtin_amdgcn_mfma_f32_16x16x32_f16(a[mi], b[ci], acc[mi][ci], 0, 0, 0);
    }
#pragma unroll
    for (int ci = 0; ci < 4; ++ci) {
        int c = wc * 64 + ci * 16 + lrow;
        float bv = nb1[c];
#pragma unroll
        for (int mi = 0; mi < 2; ++mi)
#pragma unroll
            for (int i = 0; i < 4; ++i) {
                int r = rbase + mi * 16 + quad * 4 + i;
                tbuf[r][c] = (_Float16)fmaxf(acc[mi][ci][i] + bv, 0.f);
            }
    }
    __syncthreads();

    // ===== M2: h = t1 @ w2 + b2 ; gin = q[batch] * h =====
#pragma unroll
    for (int mi = 0; mi < 2; ++mi)
#pragma unroll
        for (int ci = 0; ci < 4; ++ci) acc[mi][ci] = fz;
#pragma unroll
    for (int ki = 0; ki < 4; ++ki) {
        const int k = ki * 32 + quad * 8;
        f16x8 a[2];
#pragma unroll
        for (int mi = 0; mi < 2; ++mi)
            a[mi] = *(const f16x8*)&tbuf[rbase + mi * 16 + lrow][k];
        f16x8 b[4];
#pragma unroll
        for (int ci = 0; ci < 4; ++ci)
            b[ci] = *(const f16x8*)(wT2 + (size_t)(wc * 64 + ci * 16 + lrow) * 128 + k);
#pragma unroll
        for (int mi = 0; mi < 2; ++mi)
#pragma unroll
            for (int ci = 0; ci < 4; ++ci)
                acc[mi][ci] = __builtin_amdgcn_mfma_f32_16x16x32_f16(a[mi], b[ci], acc[mi][ci], 0, 0, 0);
    }
    f32x4 hreg[2][4];
    int grel[2][4];
#pragma unroll
    for (int mi = 0; mi < 2; ++mi)
#pragma unroll
        for (int i = 0; i < 4; ++i) {
            int r = rbase + mi * 16 + quad * 4 + i;
            grel[mi][i] = batch_t[r] - b_lo;
        }
#pragma unroll
    for (int ci = 0; ci < 4; ++ci) {
        int c = wc * 64 + ci * 16 + lrow;
        float bv = nb2[c];
#pragma unroll
        for (int mi = 0; mi < 2; ++mi)
#pragma unroll
            for (int i = 0; i < 4; ++i) {
                float h = acc[mi][ci][i] + bv;
                hreg[mi][ci][i] = h;
                int g = grel[mi][i];
                float qv = (g < GMAX) ? qs[g][c]
                                      : qglob[(size_t)(b_lo + g) * 128 + c];
                acc[mi][ci][i] = qv * h;  // gin
            }
    }
    __syncthreads();  // everyone done reading t1
#pragma unroll
    for (int ci = 0; ci < 4; ++ci) {
        int c = wc * 64 + ci * 16 + lrow;
#pragma unroll
        for (int mi = 0; mi < 2; ++mi)
#pragma unroll
            for (int i = 0; i < 4; ++i) {
                int r = rbase + mi * 16 + quad * 4 + i;
                tbuf[r][c] = (_Float16)acc[mi][ci][i];
            }
    }
    __syncthreads();

    // ===== M3: t2 = relu(gin @ gw1 + gb1) =====
#pragma unroll
    for (int mi = 0; mi < 2; ++mi)
#pragma unroll
        for (int ci = 0; ci < 4; ++ci) acc[mi][ci] = fz;
#pragma unroll
    for (int ki = 0; ki < 4; ++ki) {
        const int k = ki * 32 + quad * 8;
        f16x8 a[2];
#pragma unroll
        for (int mi = 0; mi < 2; ++mi)
            a[mi] = *(const f16x8*)&tbuf[rbase + mi * 16 + lrow][k];
        f16x8 b[4];
#pragma unroll
        for (int ci = 0; ci < 4; ++ci)
            b[ci] = *(const f16x8*)(wTg + (size_t)(wc * 64 + ci * 16 + lrow) * 128 + k);
#pragma unroll
        for (int mi = 0; mi < 2; ++mi)
#pragma unroll
            for (int ci = 0; ci < 4; ++ci)
                acc[mi][ci] = __builtin_amdgcn_mfma_f32_16x16x32_f16(a[mi], b[ci], acc[mi][ci], 0, 0, 0);
    }
#pragma unroll
    for (int ci = 0; ci < 4; ++ci) {
        int c = wc * 64 + ci * 16 + lrow;
        float bv = gb1[c];
#pragma unroll
        for (int mi = 0; mi < 2; ++mi)
#pragma unroll
            for (int i = 0; i < 4; ++i)
                acc[mi][ci][i] = fmaxf(acc[mi][ci][i] + bv, 0.f);
    }
    __syncthreads();  // everyone done reading gin
#pragma unroll
    for (int ci = 0; ci < 4; ++ci) {
        int c = wc * 64 + ci * 16 + lrow;
#pragma unroll
        for (int mi = 0; mi < 2; ++mi)
#pragma unroll
            for (int i = 0; i < 4; ++i) {
                int r = rbase + mi * 16 + quad * 4 + i;
                tbuf[r][c] = (_Float16)acc[mi][ci][i];
            }
    }
    __syncthreads();

    // ===== M4: gate = t2 @ gw2 + gb2 (broadcast-column B -> every lane holds its rows' gate) =====
    f32x4 gacc[2];
    gacc[0] = fz; gacc[1] = fz;
#pragma unroll
    for (int ki = 0; ki < 4; ++ki) {
        const int k = ki * 32 + quad * 8;
        f16x8 bg = *(const f16x8*)(g2h + k);
#pragma unroll
        for (int mi = 0; mi < 2; ++mi) {
            f16x8 a = *(const f16x8*)&tbuf[rbase + mi * 16 + lrow][k];
            gacc[mi] = __builtin_amdgcn_mfma_f32_16x16x32_f16(a, bg, gacc[mi], 0, 0, 0);
        }
    }
    const float gb2v = gb2[0];

    // ===== P,s accumulation =====
#pragma unroll
    for (int mi = 0; mi < 2; ++mi)
#pragma unroll
        for (int i = 0; i < 4; ++i) {
            int r = rbase + mi * 16 + quad * 4 + i;
            bool valid = (row0 + r) < NN;
            float e = valid ? expf(gacc[mi][i] + gb2v) : 0.f;
            int g = grel[mi][i];
            if (wc == 0 && lrow == 0) {
                if (g < GMAX) atomicAdd(&sacc[g], e);
                else atomicAdd(&s[b_lo + g], e);
            }
#pragma unroll
            for (int ci = 0; ci < 4; ++ci) {
                int c = wc * 64 + ci * 16 + lrow;
                float v = e * hreg[mi][ci][i];
                if (g < GMAX) atomicAdd(&Pacc[g][c], v);
                else atomicAdd(&P[(size_t)(b_lo + g) * 128 + c], v);
            }
        }
    __syncthreads();
    for (int idx = tid; idx < gcnt * 128; idx += 512) {
        int g = idx >> 7, c = idx & 127;
        atomicAdd(&P[(size_t)(b_lo + g) * 128 + c], Pacc[g][c]);
    }
    if (tid < gcnt) atomicAdd(&s[b_lo + tid], sacc[tid]);
}

// ---------------- finalize: out = P / (s + eps), in place ----------------
__global__ void fin_kernel(float* __restrict__ P, const float* __restrict__ s) {
    int idx = blockIdx.x * 256 + threadIdx.x;
    if (idx < NB * 128) P[idx] = P[idx] / (s[idx >> 7] + 1e-16f);
}

extern "C" void kernel_launch(void* const* d_in, const int* in_sizes, int n_in,
                              void* d_out, int out_size, void* d_ws, size_t ws_size,
                              hipStream_t stream) {
    const float* x    = (const float*)d_in[0];
    const float* u    = (const float*)d_in[1];
    const int* batch  = (const int*)d_in[2];
    const float* gw1  = (const float*)d_in[4];
    const float* gb1  = (const float*)d_in[5];
    const float* gw2  = (const float*)d_in[6];
    const float* gb2  = (const float*)d_in[7];
    const float* nw1  = (const float*)d_in[8];
    const float* nb1  = (const float*)d_in[9];
    const float* nw2  = (const float*)d_in[10];
    const float* nb2  = (const float*)d_in[11];
    const float* qw1  = (const float*)d_in[12];
    const float* qb1  = (const float*)d_in[13];
    const float* qw2  = (const float*)d_in[14];
    const float* qb2  = (const float*)d_in[15];

    char* ws = (char*)d_ws;
    float* q = (float*)ws;                               // 4 MB
    float* s = (float*)(ws + 4194304);                   // 32 KB
    _Float16* wT1 = (_Float16*)(ws + 4227072);           // 32 KB
    _Float16* wT2 = wT1 + 16384;
    _Float16* wTg = wT2 + 16384;
    _Float16* g2h = wTg + 16384;
    float* P = (float*)d_out;                            // P lives in d_out

    hipLaunchKernelGGL(prep_w, dim3(128), dim3(128), 0, stream,
                       nw1, nw2, gw1, gw2, wT1, wT2, wTg, g2h);
    hipLaunchKernelGGL(prep_q, dim3(NB / 8), dim3(128), 0, stream,
                       u, qw1, qb1, qw2, qb2, q, P, s);
    hipLaunchKernelGGL(hg_kernel, dim3((NN + TILE_M - 1) / TILE_M), dim3(512), 0, stream,
                       x, batch, q, wT1, wT2, wTg, g2h, nb1, nb2, gb1, gb2, P, s);
    hipLaunchKernelGGL(fin_kernel, dim3((NB * 128 + 255) / 256), dim3(256), 0, stream, P, s);
}

// Round 2
// 622.810 us; speedup vs baseline: 1.6570x; 1.6570x over previous
//
#include <hip/hip_runtime.h>
#include <math.h>

#define NN 500000
#define NB 8192
#define GMAX 16
#define TILE_M 128

typedef _Float16 f16x8 __attribute__((ext_vector_type(8)));
typedef float f32x4 __attribute__((ext_vector_type(4)));

__device__ inline f16x8 zero8() {
    f16x8 v;
#pragma unroll
    for (int i = 0; i < 8; ++i) v[i] = (_Float16)0.f;
    return v;
}

// ---------------- weight prep: W^T as f16 ----------------
__global__ void prep_w(const float* __restrict__ nw1, const float* __restrict__ nw2,
                       const float* __restrict__ gw1, const float* __restrict__ gw2,
                       const float* __restrict__ qw1, const float* __restrict__ qw2,
                       _Float16* __restrict__ wT1, _Float16* __restrict__ wT2,
                       _Float16* __restrict__ wTg, _Float16* __restrict__ wTq1,
                       _Float16* __restrict__ wTq2, _Float16* __restrict__ g2h) {
    int k = blockIdx.x;   // 0..127 (input dim)
    int n = threadIdx.x;  // 0..127 (output dim)
    wT1[n * 128 + k]  = (_Float16)nw1[k * 128 + n];
    wT2[n * 128 + k]  = (_Float16)nw2[k * 128 + n];
    wTg[n * 128 + k]  = (_Float16)gw1[k * 128 + n];
    wTq1[n * 128 + k] = (_Float16)qw1[k * 128 + n];
    wTq2[n * 128 + k] = (_Float16)qw2[k * 128 + n];
    if (k == 0) g2h[n] = (_Float16)gw2[n];
}

// ---------------- ques MLP via MFMA (q stored f16) + zero P,s ----------------
__launch_bounds__(512, 4)
__global__ void q_kernel(const float* __restrict__ u,
                         const _Float16* __restrict__ wTq1, const _Float16* __restrict__ wTq2,
                         const float* __restrict__ qb1, const float* __restrict__ qb2,
                         _Float16* __restrict__ q, float* __restrict__ P, float* __restrict__ s) {
    __shared__ __align__(16) _Float16 tbuf[TILE_M][136];
    const int tid  = threadIdx.x;
    const int wave = tid >> 6;
    const int lane = tid & 63;
    const int lrow = lane & 15;
    const int quad = lane >> 4;
    const int wr   = wave >> 1;
    const int wc   = wave & 1;
    const int row0 = blockIdx.x * TILE_M;
    const int rbase = wr * 32;

    // zero this block's slice of P and s
    for (int idx = tid; idx < TILE_M * 128; idx += 512) P[(size_t)row0 * 128 + idx] = 0.f;
    if (tid < TILE_M) s[row0 + tid] = 0.f;

    f32x4 acc[2][4];
    const f32x4 fz = {0.f, 0.f, 0.f, 0.f};
#pragma unroll
    for (int mi = 0; mi < 2; ++mi)
#pragma unroll
        for (int ci = 0; ci < 4; ++ci) acc[mi][ci] = fz;

    // M1: t = relu(u @ qw1 + qb1)
#pragma unroll
    for (int ki = 0; ki < 4; ++ki) {
        const int k = ki * 32 + quad * 8;
        f16x8 a[2];
#pragma unroll
        for (int mi = 0; mi < 2; ++mi) {
            int r = row0 + rbase + mi * 16 + lrow;
            const float4* up = (const float4*)(u + (size_t)r * 128 + k);
            float4 x0 = up[0], x1 = up[1];
            f16x8 af;
            af[0] = (_Float16)x0.x; af[1] = (_Float16)x0.y;
            af[2] = (_Float16)x0.z; af[3] = (_Float16)x0.w;
            af[4] = (_Float16)x1.x; af[5] = (_Float16)x1.y;
            af[6] = (_Float16)x1.z; af[7] = (_Float16)x1.w;
            a[mi] = af;
        }
        f16x8 b[4];
#pragma unroll
        for (int ci = 0; ci < 4; ++ci)
            b[ci] = *(const f16x8*)(wTq1 + (size_t)(wc * 64 + ci * 16 + lrow) * 128 + k);
#pragma unroll
        for (int mi = 0; mi < 2; ++mi)
#pragma unroll
            for (int ci = 0; ci < 4; ++ci)
                acc[mi][ci] = __builtin_amdgcn_mfma_f32_16x16x32_f16(a[mi], b[ci], acc[mi][ci], 0, 0, 0);
    }
#pragma unroll
    for (int ci = 0; ci < 4; ++ci) {
        int c = wc * 64 + ci * 16 + lrow;
        float bv = qb1[c];
#pragma unroll
        for (int mi = 0; mi < 2; ++mi)
#pragma unroll
            for (int i = 0; i < 4; ++i) {
                int r = rbase + mi * 16 + quad * 4 + i;
                tbuf[r][c] = (_Float16)fmaxf(acc[mi][ci][i] + bv, 0.f);
            }
    }
    __syncthreads();

    // M2: q = t @ qw2 + qb2
#pragma unroll
    for (int mi = 0; mi < 2; ++mi)
#pragma unroll
        for (int ci = 0; ci < 4; ++ci) acc[mi][ci] = fz;
#pragma unroll
    for (int ki = 0; ki < 4; ++ki) {
        const int k = ki * 32 + quad * 8;
        f16x8 a[2];
#pragma unroll
        for (int mi = 0; mi < 2; ++mi)
            a[mi] = *(const f16x8*)&tbuf[rbase + mi * 16 + lrow][k];
        f16x8 b[4];
#pragma unroll
        for (int ci = 0; ci < 4; ++ci)
            b[ci] = *(const f16x8*)(wTq2 + (size_t)(wc * 64 + ci * 16 + lrow) * 128 + k);
#pragma unroll
        for (int mi = 0; mi < 2; ++mi)
#pragma unroll
            for (int ci = 0; ci < 4; ++ci)
                acc[mi][ci] = __builtin_amdgcn_mfma_f32_16x16x32_f16(a[mi], b[ci], acc[mi][ci], 0, 0, 0);
    }
#pragma unroll
    for (int ci = 0; ci < 4; ++ci) {
        int c = wc * 64 + ci * 16 + lrow;
        float bv = qb2[c];
#pragma unroll
        for (int mi = 0; mi < 2; ++mi)
#pragma unroll
            for (int i = 0; i < 4; ++i) {
                int r = row0 + rbase + mi * 16 + quad * 4 + i;
                q[(size_t)r * 128 + c] = (_Float16)(acc[mi][ci][i] + bv);
            }
    }
}

// ---------------- fused node-MLP + gate + MFMA segmented pooling ----------------
__launch_bounds__(512, 4)
__global__ void hg_kernel(const float* __restrict__ x, const int* __restrict__ batch,
                          const _Float16* __restrict__ qglob,
                          const _Float16* __restrict__ wT1, const _Float16* __restrict__ wT2,
                          const _Float16* __restrict__ wTg, const _Float16* __restrict__ g2h,
                          const float* __restrict__ nb1, const float* __restrict__ nb2,
                          const float* __restrict__ gb1, const float* __restrict__ gb2,
                          float* __restrict__ P, float* __restrict__ s) {
    __shared__ __align__(16) _Float16 tbuf[TILE_M][136];  // reused: t1 -> gin -> t2 -> H^T
    __shared__ float qs[GMAX][132];
    __shared__ __align__(16) _Float16 E_sh[GMAX][136];    // selector: E[g][r] = e_r * delta(batch_r==g)
    __shared__ int batch_t[TILE_M];
    __shared__ int maxrel_sh;

    const int tid  = threadIdx.x;
    const int wave = tid >> 6;
    const int lane = tid & 63;
    const int lrow = lane & 15;
    const int quad = lane >> 4;
    const int wr   = wave >> 1;  // 0..3  (32-row group)
    const int wc   = wave & 1;   // 0..1  (64-col group)
    const int row0 = blockIdx.x * TILE_M;
    const int rbase = wr * 32;

    if (tid < TILE_M) {
        int gr = row0 + tid;
        batch_t[tid] = (gr < NN) ? batch[gr] : batch[NN - 1];
    }
    if (tid == 0) maxrel_sh = 0;
    // zero E_sh
    for (int idx = tid; idx < GMAX * 136 / 2; idx += 512) ((float*)E_sh)[idx] = 0.f;
    __syncthreads();
    const int b_lo = batch_t[0];
    if (tid < TILE_M) atomicMax(&maxrel_sh, batch_t[tid] - b_lo);
    __syncthreads();
    const int maxrel = maxrel_sh;
    const int gcnt = min(maxrel + 1, GMAX);
    for (int idx = tid; idx < gcnt * 128; idx += 512) {
        int g = idx >> 7, c = idx & 127;
        qs[g][c] = (float)qglob[(size_t)(b_lo + g) * 128 + c];
    }
    __syncthreads();

    f32x4 acc[2][4];
    const f32x4 fz = {0.f, 0.f, 0.f, 0.f};
#pragma unroll
    for (int mi = 0; mi < 2; ++mi)
#pragma unroll
        for (int ci = 0; ci < 4; ++ci) acc[mi][ci] = fz;

    // ===== M1: t1 = relu(x @ w1 + b1) -> tbuf =====
#pragma unroll
    for (int ki = 0; ki < 4; ++ki) {
        const int k = ki * 32 + quad * 8;
        f16x8 a[2];
#pragma unroll
        for (int mi = 0; mi < 2; ++mi) {
            int r = row0 + rbase + mi * 16 + lrow;
            if (r < NN) {
                const float4* xp = (const float4*)(x + (size_t)r * 128 + k);
                float4 x0 = xp[0], x1 = xp[1];
                f16x8 af;
                af[0] = (_Float16)x0.x; af[1] = (_Float16)x0.y;
                af[2] = (_Float16)x0.z; af[3] = (_Float16)x0.w;
                af[4] = (_Float16)x1.x; af[5] = (_Float16)x1.y;
                af[6] = (_Float16)x1.z; af[7] = (_Float16)x1.w;
                a[mi] = af;
            } else {
                a[mi] = zero8();
            }
        }
        f16x8 b[4];
#pragma unroll
        for (int ci = 0; ci < 4; ++ci)
            b[ci] = *(const f16x8*)(wT1 + (size_t)(wc * 64 + ci * 16 + lrow) * 128 + k);
#pragma unroll
        for (int mi = 0; mi < 2; ++mi)
#pragma unroll
            for (int ci = 0; ci < 4; ++ci)
                acc[mi][ci] = __builtin_amdgcn_mfma_f32_16x16x32_f16(a[mi], b[ci], acc[mi][ci], 0, 0, 0);
    }
#pragma unroll
    for (int ci = 0; ci < 4; ++ci) {
        int c = wc * 64 + ci * 16 + lrow;
        float bv = nb1[c];
#pragma unroll
        for (int mi = 0; mi < 2; ++mi)
#pragma unroll
            for (int i = 0; i < 4; ++i) {
                int r = rbase + mi * 16 + quad * 4 + i;
                tbuf[r][c] = (_Float16)fmaxf(acc[mi][ci][i] + bv, 0.f);
            }
    }
    __syncthreads();

    // ===== M2: h = t1 @ w2 + b2 ; gin = q[batch] * h =====
#pragma unroll
    for (int mi = 0; mi < 2; ++mi)
#pragma unroll
        for (int ci = 0; ci < 4; ++ci) acc[mi][ci] = fz;
#pragma unroll
    for (int ki = 0; ki < 4; ++ki) {
        const int k = ki * 32 + quad * 8;
        f16x8 a[2];
#pragma unroll
        for (int mi = 0; mi < 2; ++mi)
            a[mi] = *(const f16x8*)&tbuf[rbase + mi * 16 + lrow][k];
        f16x8 b[4];
#pragma unroll
        for (int ci = 0; ci < 4; ++ci)
            b[ci] = *(const f16x8*)(wT2 + (size_t)(wc * 64 + ci * 16 + lrow) * 128 + k);
#pragma unroll
        for (int mi = 0; mi < 2; ++mi)
#pragma unroll
            for (int ci = 0; ci < 4; ++ci)
                acc[mi][ci] = __builtin_amdgcn_mfma_f32_16x16x32_f16(a[mi], b[ci], acc[mi][ci], 0, 0, 0);
    }
    f32x4 hreg[2][4];
    int grel[2][4];
#pragma unroll
    for (int mi = 0; mi < 2; ++mi)
#pragma unroll
        for (int i = 0; i < 4; ++i) {
            int r = rbase + mi * 16 + quad * 4 + i;
            grel[mi][i] = batch_t[r] - b_lo;
        }
#pragma unroll
    for (int ci = 0; ci < 4; ++ci) {
        int c = wc * 64 + ci * 16 + lrow;
        float bv = nb2[c];
#pragma unroll
        for (int mi = 0; mi < 2; ++mi)
#pragma unroll
            for (int i = 0; i < 4; ++i) {
                float h = acc[mi][ci][i] + bv;
                hreg[mi][ci][i] = h;
                int g = grel[mi][i];
                float qv = (g < GMAX) ? qs[g][c]
                                      : (float)qglob[(size_t)(b_lo + g) * 128 + c];
                acc[mi][ci][i] = qv * h;  // gin
            }
    }
    __syncthreads();  // everyone done reading t1
#pragma unroll
    for (int ci = 0; ci < 4; ++ci) {
        int c = wc * 64 + ci * 16 + lrow;
#pragma unroll
        for (int mi = 0; mi < 2; ++mi)
#pragma unroll
            for (int i = 0; i < 4; ++i) {
                int r = rbase + mi * 16 + quad * 4 + i;
                tbuf[r][c] = (_Float16)acc[mi][ci][i];
            }
    }
    __syncthreads();

    // ===== M3: t2 = relu(gin @ gw1 + gb1) =====
#pragma unroll
    for (int mi = 0; mi < 2; ++mi)
#pragma unroll
        for (int ci = 0; ci < 4; ++ci) acc[mi][ci] = fz;
#pragma unroll
    for (int ki = 0; ki < 4; ++ki) {
        const int k = ki * 32 + quad * 8;
        f16x8 a[2];
#pragma unroll
        for (int mi = 0; mi < 2; ++mi)
            a[mi] = *(const f16x8*)&tbuf[rbase + mi * 16 + lrow][k];
        f16x8 b[4];
#pragma unroll
        for (int ci = 0; ci < 4; ++ci)
            b[ci] = *(const f16x8*)(wTg + (size_t)(wc * 64 + ci * 16 + lrow) * 128 + k);
#pragma unroll
        for (int mi = 0; mi < 2; ++mi)
#pragma unroll
            for (int ci = 0; ci < 4; ++ci)
                acc[mi][ci] = __builtin_amdgcn_mfma_f32_16x16x32_f16(a[mi], b[ci], acc[mi][ci], 0, 0, 0);
    }
#pragma unroll
    for (int ci = 0; ci < 4; ++ci) {
        int c = wc * 64 + ci * 16 + lrow;
        float bv = gb1[c];
#pragma unroll
        for (int mi = 0; mi < 2; ++mi)
#pragma unroll
            for (int i = 0; i < 4; ++i)
                acc[mi][ci][i] = fmaxf(acc[mi][ci][i] + bv, 0.f);
    }
    __syncthreads();  // everyone done reading gin
#pragma unroll
    for (int ci = 0; ci < 4; ++ci) {
        int c = wc * 64 + ci * 16 + lrow;
#pragma unroll
        for (int mi = 0; mi < 2; ++mi)
#pragma unroll
            for (int i = 0; i < 4; ++i) {
                int r = rbase + mi * 16 + quad * 4 + i;
                tbuf[r][c] = (_Float16)acc[mi][ci][i];
            }
    }
    __syncthreads();

    // ===== M4: gate = t2 @ gw2 + gb2 (broadcast-column B) =====
    f32x4 gacc[2];
    gacc[0] = fz; gacc[1] = fz;
#pragma unroll
    for (int ki = 0; ki < 4; ++ki) {
        const int k = ki * 32 + quad * 8;
        f16x8 bg = *(const f16x8*)(g2h + k);
#pragma unroll
        for (int mi = 0; mi < 2; ++mi) {
            f16x8 a = *(const f16x8*)&tbuf[rbase + mi * 16 + lrow][k];
            gacc[mi] = __builtin_amdgcn_mfma_f32_16x16x32_f16(a, bg, gacc[mi], 0, 0, 0);
        }
    }
    const float gb2v = gb2[0];

    // ===== e scatter into E_sh (+ rare g>=GMAX fallback) =====
#pragma unroll
    for (int mi = 0; mi < 2; ++mi)
#pragma unroll
        for (int i = 0; i < 4; ++i) {
            int r = rbase + mi * 16 + quad * 4 + i;
            bool valid = (row0 + r) < NN;
            float e = valid ? expf(gacc[mi][i] + gb2v) : 0.f;
            int g = grel[mi][i];
            if (g < GMAX) {
                if (wc == 0 && lrow == 0) E_sh[g][r] = (_Float16)e;
            } else {  // pathological: >16 graphs in one tile
                if (wc == 0 && lrow == 0) atomicAdd(&s[b_lo + g], e);
#pragma unroll
                for (int ci = 0; ci < 4; ++ci) {
                    int c = wc * 64 + ci * 16 + lrow;
                    atomicAdd(&P[(size_t)(b_lo + g) * 128 + c], e * hreg[mi][ci][i]);
                }
            }
        }
    __syncthreads();  // t2 reads done + E_sh visible

    // ===== store H^T into tbuf =====
#pragma unroll
    for (int ci = 0; ci < 4; ++ci) {
        int c = wc * 64 + ci * 16 + lrow;
#pragma unroll
        for (int mi = 0; mi < 2; ++mi)
#pragma unroll
            for (int i = 0; i < 4; ++i) {
                int r = rbase + mi * 16 + quad * 4 + i;
                tbuf[c][r] = (_Float16)hreg[mi][ci][i];
            }
    }
    __syncthreads();

    // ===== pooling: P_tile = E @ H  (each wave: 16-col slice), s = E @ 1 =====
    f32x4 pacc = fz;
    f32x4 spool = fz;
    f16x8 bO;
#pragma unroll
    for (int j = 0; j < 8; ++j) bO[j] = (lrow == 0) ? (_Float16)1.f : (_Float16)0.f;
#pragma unroll
    for (int ki = 0; ki < 4; ++ki) {
        const int k = ki * 32 + quad * 8;
        f16x8 aE = *(const f16x8*)&E_sh[lrow][k];
        f16x8 bH = *(const f16x8*)&tbuf[wave * 16 + lrow][k];
        pacc = __builtin_amdgcn_mfma_f32_16x16x32_f16(aE, bH, pacc, 0, 0, 0);
        if (wave == 0)
            spool = __builtin_amdgcn_mfma_f32_16x16x32_f16(aE, bO, spool, 0, 0, 0);
    }
#pragma unroll
    for (int i = 0; i < 4; ++i) {
        int g = quad * 4 + i;
        if (g < gcnt)
            atomicAdd(&P[(size_t)(b_lo + g) * 128 + wave * 16 + lrow], pacc[i]);
    }
    if (wave == 0 && lrow == 0) {
#pragma unroll
        for (int i = 0; i < 4; ++i) {
            int g = quad * 4 + i;
            if (g < gcnt) atomicAdd(&s[b_lo + g], spool[i]);
        }
    }
}

// ---------------- finalize: out = P / (s + eps), in place ----------------
__global__ void fin_kernel(float* __restrict__ P, const float* __restrict__ s) {
    int idx = blockIdx.x * 256 + threadIdx.x;
    if (idx < NB * 128) P[idx] = P[idx] / (s[idx >> 7] + 1e-16f);
}

extern "C" void kernel_launch(void* const* d_in, const int* in_sizes, int n_in,
                              void* d_out, int out_size, void* d_ws, size_t ws_size,
                              hipStream_t stream) {
    const float* x    = (const float*)d_in[0];
    const float* u    = (const float*)d_in[1];
    const int* batch  = (const int*)d_in[2];
    const float* gw1  = (const float*)d_in[4];
    const float* gb1  = (const float*)d_in[5];
    const float* gw2  = (const float*)d_in[6];
    const float* gb2  = (const float*)d_in[7];
    const float* nw1  = (const float*)d_in[8];
    const float* nb1  = (const float*)d_in[9];
    const float* nw2  = (const float*)d_in[10];
    const float* nb2  = (const float*)d_in[11];
    const float* qw1  = (const float*)d_in[12];
    const float* qb1  = (const float*)d_in[13];
    const float* qw2  = (const float*)d_in[14];
    const float* qb2  = (const float*)d_in[15];

    char* ws = (char*)d_ws;
    _Float16* q = (_Float16*)ws;                         // 2 MB (f16)
    float* s = (float*)(ws + 2097152);                   // 32 KB
    _Float16* wT1 = (_Float16*)(ws + 2129920);           // 5 x 32 KB + g2h
    _Float16* wT2  = wT1 + 16384;
    _Float16* wTg  = wT2 + 16384;
    _Float16* wTq1 = wTg + 16384;
    _Float16* wTq2 = wTq1 + 16384;
    _Float16* g2h  = wTq2 + 16384;
    float* P = (float*)d_out;                            // P lives in d_out

    hipLaunchKernelGGL(prep_w, dim3(128), dim3(128), 0, stream,
                       nw1, nw2, gw1, gw2, qw1, qw2, wT1, wT2, wTg, wTq1, wTq2, g2h);
    hipLaunchKernelGGL(q_kernel, dim3(NB / TILE_M), dim3(512), 0, stream,
                       u, wTq1, wTq2, qb1, qb2, q, P, s);
    hipLaunchKernelGGL(hg_kernel, dim3((NN + TILE_M - 1) / TILE_M), dim3(512), 0, stream,
                       x, batch, q, wT1, wT2, wTg, g2h, nb1, nb2, gb1, gb2, P, s);
    hipLaunchKernelGGL(fin_kernel, dim3((NB * 128 + 255) / 256), dim3(256), 0, stream, P, s);
}

// Round 4
// 556.977 us; speedup vs baseline: 1.8529x; 1.1182x over previous
//
#include <hip/hip_runtime.h>
#include <math.h>

#define NN 500000
#define NB 8192
#define GMAX 16

typedef _Float16 f16x8 __attribute__((ext_vector_type(8)));
typedef __fp16 fp16x2 __attribute__((ext_vector_type(2)));
typedef float f32x4 __attribute__((ext_vector_type(4)));

__device__ inline f16x8 cvt8(float4 a, float4 b) {
    union { fp16x2 p[4]; f16x8 r; } u;
    u.p[0] = __builtin_amdgcn_cvt_pkrtz(a.x, a.y);
    u.p[1] = __builtin_amdgcn_cvt_pkrtz(a.z, a.w);
    u.p[2] = __builtin_amdgcn_cvt_pkrtz(b.x, b.y);
    u.p[3] = __builtin_amdgcn_cvt_pkrtz(b.z, b.w);
    return u.r;
}

// ---------------- weight prep: W^T as f16 ----------------
__global__ void prep_w(const float* __restrict__ nw1, const float* __restrict__ nw2,
                       const float* __restrict__ gw1, const float* __restrict__ gw2,
                       const float* __restrict__ qw1, const float* __restrict__ qw2,
                       _Float16* __restrict__ wT1, _Float16* __restrict__ wT2,
                       _Float16* __restrict__ wTg, _Float16* __restrict__ wTq1,
                       _Float16* __restrict__ wTq2, _Float16* __restrict__ g2h) {
    int k = blockIdx.x;   // input dim
    int n = threadIdx.x;  // output dim
    wT1[n * 128 + k]  = (_Float16)nw1[k * 128 + n];
    wT2[n * 128 + k]  = (_Float16)nw2[k * 128 + n];
    wTg[n * 128 + k]  = (_Float16)gw1[k * 128 + n];
    wTq1[n * 128 + k] = (_Float16)qw1[k * 128 + n];
    wTq2[n * 128 + k] = (_Float16)qw2[k * 128 + n];
    if (k == 0) g2h[n] = (_Float16)gw2[n];
}

// ---------------- ques MLP via MFMA (q stored f16) + zero Ppre,s ----------------
__launch_bounds__(512, 4)
__global__ void q_kernel(const float* __restrict__ u,
                         const _Float16* __restrict__ wTq1, const _Float16* __restrict__ wTq2,
                         const float* __restrict__ qb1, const float* __restrict__ qb2,
                         _Float16* __restrict__ q, float* __restrict__ Ppre, float* __restrict__ s) {
    __shared__ __align__(16) _Float16 tbuf[128][136];
    const int tid  = threadIdx.x;
    const int wave = tid >> 6;
    const int lane = tid & 63;
    const int lrow = lane & 15;
    const int quad = lane >> 4;
    const int wr   = wave >> 1;
    const int wc   = wave & 1;
    const int row0 = blockIdx.x * 128;
    const int rbase = wr * 32;

    for (int idx = tid; idx < 128 * 128; idx += 512) Ppre[(size_t)row0 * 128 + idx] = 0.f;
    if (tid < 128) s[row0 + tid] = 0.f;

    f32x4 acc[2][4];
    const f32x4 fz = {0.f, 0.f, 0.f, 0.f};
#pragma unroll
    for (int mi = 0; mi < 2; ++mi)
#pragma unroll
        for (int ci = 0; ci < 4; ++ci) acc[mi][ci] = fz;

#pragma unroll
    for (int ki = 0; ki < 4; ++ki) {
        const int k = ki * 32 + quad * 8;
        f16x8 a[2];
#pragma unroll
        for (int mi = 0; mi < 2; ++mi) {
            int r = row0 + rbase + mi * 16 + lrow;
            const float4* up = (const float4*)(u + (size_t)r * 128 + k);
            a[mi] = cvt8(up[0], up[1]);
        }
        f16x8 b[4];
#pragma unroll
        for (int ci = 0; ci < 4; ++ci)
            b[ci] = *(const f16x8*)(wTq1 + (size_t)(wc * 64 + ci * 16 + lrow) * 128 + k);
#pragma unroll
        for (int mi = 0; mi < 2; ++mi)
#pragma unroll
            for (int ci = 0; ci < 4; ++ci)
                acc[mi][ci] = __builtin_amdgcn_mfma_f32_16x16x32_f16(a[mi], b[ci], acc[mi][ci], 0, 0, 0);
    }
#pragma unroll
    for (int ci = 0; ci < 4; ++ci) {
        int c = wc * 64 + ci * 16 + lrow;
        float bv = qb1[c];
#pragma unroll
        for (int mi = 0; mi < 2; ++mi)
#pragma unroll
            for (int i = 0; i < 4; ++i) {
                int r = rbase + mi * 16 + quad * 4 + i;
                tbuf[r][c] = (_Float16)fmaxf(acc[mi][ci][i] + bv, 0.f);
            }
    }
    __syncthreads();

#pragma unroll
    for (int mi = 0; mi < 2; ++mi)
#pragma unroll
        for (int ci = 0; ci < 4; ++ci) acc[mi][ci] = fz;
#pragma unroll
    for (int ki = 0; ki < 4; ++ki) {
        const int k = ki * 32 + quad * 8;
        f16x8 a[2];
#pragma unroll
        for (int mi = 0; mi < 2; ++mi)
            a[mi] = *(const f16x8*)&tbuf[rbase + mi * 16 + lrow][k];
        f16x8 b[4];
#pragma unroll
        for (int ci = 0; ci < 4; ++ci)
            b[ci] = *(const f16x8*)(wTq2 + (size_t)(wc * 64 + ci * 16 + lrow) * 128 + k);
#pragma unroll
        for (int mi = 0; mi < 2; ++mi)
#pragma unroll
            for (int ci = 0; ci < 4; ++ci)
                acc[mi][ci] = __builtin_amdgcn_mfma_f32_16x16x32_f16(a[mi], b[ci], acc[mi][ci], 0, 0, 0);
    }
#pragma unroll
    for (int ci = 0; ci < 4; ++ci) {
        int c = wc * 64 + ci * 16 + lrow;
        float bv = qb2[c];
#pragma unroll
        for (int mi = 0; mi < 2; ++mi)
#pragma unroll
            for (int i = 0; i < 4; ++i) {
                int r = row0 + rbase + mi * 16 + quad * 4 + i;
                q[(size_t)r * 128 + c] = (_Float16)(acc[mi][ci][i] + bv);
            }
    }
}

// ---------------- fused node-MLP + gate + pool-over-t1 ----------------
__launch_bounds__(256, 4)
__global__ void hg_kernel(const float* __restrict__ x, const int* __restrict__ batch,
                          const _Float16* __restrict__ qglob,
                          const _Float16* __restrict__ wT1, const _Float16* __restrict__ wT2,
                          const _Float16* __restrict__ wTg, const _Float16* __restrict__ g2h,
                          const float* __restrict__ nb1, const float* __restrict__ nb2,
                          const float* __restrict__ gb1, const float* __restrict__ gb2,
                          float* __restrict__ Ppre, float* __restrict__ s) {
    __shared__ __align__(16) _Float16 t1buf[64][136];    // persists: M1 out -> M2 in -> pooling B
    __shared__ __align__(16) _Float16 scratch[64][136];  // gin only
    __shared__ __align__(16) _Float16 qsE[GMAX][136];    // union: qs (f16) then E selector
    __shared__ float gpart[2][64];
    __shared__ float sacc[GMAX];
    __shared__ int batch_t[64];
    __shared__ int maxrel_sh;

    const int tid  = threadIdx.x;
    const int wave = tid >> 6;   // 0..3
    const int lane = tid & 63;
    const int lrow = lane & 15;
    const int quad = lane >> 4;
    const int wr   = wave >> 1;  // 0..1
    const int wc   = wave & 1;
    const int row0 = blockIdx.x * 64;
    const int rbase = wr * 32;

    // ---- issue x loads immediately (branchless, clamped; garbage rows get e=0) ----
    float4 xraw[4][2][2];
#pragma unroll
    for (int ki = 0; ki < 4; ++ki)
#pragma unroll
        for (int mi = 0; mi < 2; ++mi) {
            int r = min(row0 + rbase + mi * 16 + lrow, NN - 1);
            const float4* xp = (const float4*)(x + (size_t)r * 128 + ki * 32 + quad * 8);
            xraw[ki][mi][0] = xp[0];
            xraw[ki][mi][1] = xp[1];
        }

    // ---- setup: batch window, b_lo, maxrel (wave 0 only) ----
    if (wave == 0) {
        int bv = batch[min(row0 + lane, NN - 1)];
        batch_t[lane] = bv;
        int b0 = __shfl(bv, 0, 64);
        int rel = bv - b0;
#pragma unroll
        for (int off = 32; off >= 1; off >>= 1) rel = max(rel, __shfl_xor(rel, off, 64));
        if (lane == 0) maxrel_sh = rel;
    }
    __syncthreads();  // bar0
    const int b_lo = batch_t[0];
    const int gcnt = min(maxrel_sh + 1, GMAX);

    // qs: gather q rows for graphs in window (consumed after bar1)
    for (int idx = tid; idx < gcnt * 16; idx += 256)
        *(f16x8*)&qsE[idx >> 4][(idx & 15) * 8] =
            *(const f16x8*)(qglob + (size_t)(b_lo + (idx >> 4)) * 128 + (idx & 15) * 8);

    int grel[2][4];
#pragma unroll
    for (int mi = 0; mi < 2; ++mi)
#pragma unroll
        for (int i = 0; i < 4; ++i)
            grel[mi][i] = batch_t[rbase + mi * 16 + quad * 4 + i] - b_lo;

    // convert x to f16 fragments
    f16x8 a16[4][2];
#pragma unroll
    for (int ki = 0; ki < 4; ++ki)
#pragma unroll
        for (int mi = 0; mi < 2; ++mi)
            a16[ki][mi] = cvt8(xraw[ki][mi][0], xraw[ki][mi][1]);

    f32x4 acc[2][4];
    const f32x4 fz = {0.f, 0.f, 0.f, 0.f};
#pragma unroll
    for (int mi = 0; mi < 2; ++mi)
#pragma unroll
        for (int ci = 0; ci < 4; ++ci) acc[mi][ci] = fz;

    // ===== M1: t1 = relu(x @ w1 + b1) -> t1buf =====
#pragma unroll
    for (int ki = 0; ki < 4; ++ki) {
        const int k = ki * 32 + quad * 8;
        f16x8 b[4];
#pragma unroll
        for (int ci = 0; ci < 4; ++ci)
            b[ci] = *(const f16x8*)(wT1 + (size_t)(wc * 64 + ci * 16 + lrow) * 128 + k);
#pragma unroll
        for (int mi = 0; mi < 2; ++mi)
#pragma unroll
            for (int ci = 0; ci < 4; ++ci)
                acc[mi][ci] = __builtin_amdgcn_mfma_f32_16x16x32_f16(a16[ki][mi], b[ci], acc[mi][ci], 0, 0, 0);
    }
#pragma unroll
    for (int ci = 0; ci < 4; ++ci) {
        int c = wc * 64 + ci * 16 + lrow;
        float bv = nb1[c];
#pragma unroll
        for (int mi = 0; mi < 2; ++mi)
#pragma unroll
            for (int i = 0; i < 4; ++i) {
                int r = rbase + mi * 16 + quad * 4 + i;
                t1buf[r][c] = (_Float16)fmaxf(acc[mi][ci][i] + bv, 0.f);
            }
    }
    __syncthreads();  // bar1: t1 + qs visible

    // ===== M2: h = t1 @ w2 + b2 ; gin = q[batch] * h -> scratch =====
#pragma unroll
    for (int mi = 0; mi < 2; ++mi)
#pragma unroll
        for (int ci = 0; ci < 4; ++ci) acc[mi][ci] = fz;
#pragma unroll
    for (int ki = 0; ki < 4; ++ki) {
        const int k = ki * 32 + quad * 8;
        f16x8 a[2];
#pragma unroll
        for (int mi = 0; mi < 2; ++mi)
            a[mi] = *(const f16x8*)&t1buf[rbase + mi * 16 + lrow][k];
        f16x8 b[4];
#pragma unroll
        for (int ci = 0; ci < 4; ++ci)
            b[ci] = *(const f16x8*)(wT2 + (size_t)(wc * 64 + ci * 16 + lrow) * 128 + k);
#pragma unroll
        for (int mi = 0; mi < 2; ++mi)
#pragma unroll
            for (int ci = 0; ci < 4; ++ci)
                acc[mi][ci] = __builtin_amdgcn_mfma_f32_16x16x32_f16(a[mi], b[ci], acc[mi][ci], 0, 0, 0);
    }
#pragma unroll
    for (int ci = 0; ci < 4; ++ci) {
        int c = wc * 64 + ci * 16 + lrow;
        float bv = nb2[c];
#pragma unroll
        for (int mi = 0; mi < 2; ++mi)
#pragma unroll
            for (int i = 0; i < 4; ++i) {
                int r = rbase + mi * 16 + quad * 4 + i;
                float h = acc[mi][ci][i] + bv;
                int g = grel[mi][i];
                float qv = (g < GMAX) ? (float)qsE[g][c]
                                      : (float)qglob[(size_t)(b_lo + g) * 128 + c];
                scratch[r][c] = (_Float16)(qv * h);
            }
    }
    __syncthreads();  // bar2: gin visible, qs reads done

    // zero E + sacc (visible after bar3)
    for (int idx = tid; idx < GMAX * 136 / 2; idx += 256) ((float*)qsE)[idx] = 0.f;
    if (tid < GMAX) sacc[tid] = 0.f;

    // ===== M3: t2 = relu(gin @ gw1 + gb1); gate partial via gw2 dot + shuffle =====
#pragma unroll
    for (int mi = 0; mi < 2; ++mi)
#pragma unroll
        for (int ci = 0; ci < 4; ++ci) acc[mi][ci] = fz;
    float g2hreg[4];
#pragma unroll
    for (int ci = 0; ci < 4; ++ci) g2hreg[ci] = (float)g2h[wc * 64 + ci * 16 + lrow];
#pragma unroll
    for (int ki = 0; ki < 4; ++ki) {
        const int k = ki * 32 + quad * 8;
        f16x8 a[2];
#pragma unroll
        for (int mi = 0; mi < 2; ++mi)
            a[mi] = *(const f16x8*)&scratch[rbase + mi * 16 + lrow][k];
        f16x8 b[4];
#pragma unroll
        for (int ci = 0; ci < 4; ++ci)
            b[ci] = *(const f16x8*)(wTg + (size_t)(wc * 64 + ci * 16 + lrow) * 128 + k);
#pragma unroll
        for (int mi = 0; mi < 2; ++mi)
#pragma unroll
            for (int ci = 0; ci < 4; ++ci)
                acc[mi][ci] = __builtin_amdgcn_mfma_f32_16x16x32_f16(a[mi], b[ci], acc[mi][ci], 0, 0, 0);
    }
    float p[2][4] = {{0.f, 0.f, 0.f, 0.f}, {0.f, 0.f, 0.f, 0.f}};
#pragma unroll
    for (int ci = 0; ci < 4; ++ci) {
        int c = wc * 64 + ci * 16 + lrow;
        float bv = gb1[c];
        float w = g2hreg[ci];
#pragma unroll
        for (int mi = 0; mi < 2; ++mi)
#pragma unroll
            for (int i = 0; i < 4; ++i)
                p[mi][i] = fmaf(fmaxf(acc[mi][ci][i] + bv, 0.f), w, p[mi][i]);
    }
#pragma unroll
    for (int off = 1; off <= 8; off <<= 1)
#pragma unroll
        for (int mi = 0; mi < 2; ++mi)
#pragma unroll
            for (int i = 0; i < 4; ++i)
                p[mi][i] += __shfl_xor(p[mi][i], off, 64);
    if (lrow == 0) {
#pragma unroll
        for (int mi = 0; mi < 2; ++mi)
#pragma unroll
            for (int i = 0; i < 4; ++i)
                gpart[wc][rbase + mi * 16 + quad * 4 + i] = p[mi][i];
    }
    __syncthreads();  // bar3: gpart + E-zero visible

    // ===== gate -> e -> E selector (one thread per row) =====
    const float gb2v = gb2[0];
    if (tid < 64) {
        int r = tid;
        int g = batch_t[r] - b_lo;
        bool valid = (row0 + r) < NN;
        float e = valid ? __expf(gpart[0][r] + gpart[1][r] + gb2v) : 0.f;
        if (g < GMAX) {
            qsE[g][r] = (_Float16)e;
            atomicAdd(&sacc[g], e);
        } else if (valid) {  // pathological >16 graphs per 64-row window
            atomicAdd(&s[b_lo + g], e);
            for (int c = 0; c < 128; ++c)
                atomicAdd(&Ppre[(size_t)(b_lo + g) * 128 + c], e * (float)t1buf[r][c]);
        }
    }
    __syncthreads();  // bar4: E visible

    // ===== pooling: Ppre_tile = E(16x64) @ T1(64x128), each wave 32 cols =====
    f16x8 aE[2];
#pragma unroll
    for (int ki = 0; ki < 2; ++ki)
        aE[ki] = *(const f16x8*)&qsE[lrow][ki * 32 + quad * 8];
    f32x4 pacc[2] = {fz, fz};
#pragma unroll
    for (int ci2 = 0; ci2 < 2; ++ci2) {
        int col = wave * 32 + ci2 * 16 + lrow;
#pragma unroll
        for (int ki = 0; ki < 2; ++ki) {
            f16x8 bh;
#pragma unroll
            for (int j = 0; j < 8; ++j) bh[j] = t1buf[ki * 32 + quad * 8 + j][col];
            pacc[ci2] = __builtin_amdgcn_mfma_f32_16x16x32_f16(aE[ki], bh, pacc[ci2], 0, 0, 0);
        }
    }
#pragma unroll
    for (int ci2 = 0; ci2 < 2; ++ci2)
#pragma unroll
        for (int i = 0; i < 4; ++i) {
            int g = quad * 4 + i;
            if (g < gcnt)
                atomicAdd(&Ppre[(size_t)(b_lo + g) * 128 + wave * 32 + ci2 * 16 + lrow], pacc[ci2][i]);
        }
    if (tid < gcnt) atomicAdd(&s[b_lo + tid], sacc[tid]);
}

// ---------------- finalize: out = (Ppre @ w2 + s*b2) / (s + eps) ----------------
__launch_bounds__(512, 4)
__global__ void fin_kernel(const float* __restrict__ Ppre, const float* __restrict__ s,
                           const _Float16* __restrict__ wT2, const float* __restrict__ nb2,
                           float* __restrict__ out) {
    const int tid  = threadIdx.x;
    const int wave = tid >> 6;
    const int lane = tid & 63;
    const int lrow = lane & 15;
    const int quad = lane >> 4;
    const int wr   = wave >> 1;
    const int wc   = wave & 1;
    const int row0 = blockIdx.x * 128;
    const int rbase = wr * 32;

    f32x4 acc[2][4];
    const f32x4 fz = {0.f, 0.f, 0.f, 0.f};
#pragma unroll
    for (int mi = 0; mi < 2; ++mi)
#pragma unroll
        for (int ci = 0; ci < 4; ++ci) acc[mi][ci] = fz;
#pragma unroll
    for (int ki = 0; ki < 4; ++ki) {
        const int k = ki * 32 + quad * 8;
        f16x8 a[2];
#pragma unroll
        for (int mi = 0; mi < 2; ++mi) {
            int r = row0 + rbase + mi * 16 + lrow;
            const float4* pp = (const float4*)(Ppre + (size_t)r * 128 + k);
            a[mi] = cvt8(pp[0], pp[1]);
        }
        f16x8 b[4];
#pragma unroll
        for (int ci = 0; ci < 4; ++ci)
            b[ci] = *(const f16x8*)(wT2 + (size_t)(wc * 64 + ci * 16 + lrow) * 128 + k);
#pragma unroll
        for (int mi = 0; mi < 2; ++mi)
#pragma unroll
            for (int ci = 0; ci < 4; ++ci)
                acc[mi][ci] = __builtin_amdgcn_mfma_f32_16x16x32_f16(a[mi], b[ci], acc[mi][ci], 0, 0, 0);
    }
    float sv[2][4], rinv[2][4];
#pragma unroll
    for (int mi = 0; mi < 2; ++mi)
#pragma unroll
        for (int i = 0; i < 4; ++i) {
            int r = row0 + rbase + mi * 16 + quad * 4 + i;
            sv[mi][i] = s[r];
            rinv[mi][i] = 1.f / (sv[mi][i] + 1e-16f);
        }
#pragma unroll
    for (int ci = 0; ci < 4; ++ci) {
        int c = wc * 64 + ci * 16 + lrow;
        float bv = nb2[c];
#pragma unroll
        for (int mi = 0; mi < 2; ++mi)
#pragma unroll
            for (int i = 0; i < 4; ++i) {
                int r = row0 + rbase + mi * 16 + quad * 4 + i;
                out[(size_t)r * 128 + c] = (acc[mi][ci][i] + sv[mi][i] * bv) * rinv[mi][i];
            }
    }
}

extern "C" void kernel_launch(void* const* d_in, const int* in_sizes, int n_in,
                              void* d_out, int out_size, void* d_ws, size_t ws_size,
                              hipStream_t stream) {
    const float* x    = (const float*)d_in[0];
    const float* u    = (const float*)d_in[1];
    const int* batch  = (const int*)d_in[2];
    const float* gw1  = (const float*)d_in[4];
    const float* gb1  = (const float*)d_in[5];
    const float* gw2  = (const float*)d_in[6];
    const float* gb2  = (const float*)d_in[7];
    const float* nw1  = (const float*)d_in[8];
    const float* nb1  = (const float*)d_in[9];
    const float* nw2  = (const float*)d_in[10];
    const float* nb2  = (const float*)d_in[11];
    const float* qw1  = (const float*)d_in[12];
    const float* qb1  = (const float*)d_in[13];
    const float* qw2  = (const float*)d_in[14];
    const float* qb2  = (const float*)d_in[15];

    char* ws = (char*)d_ws;
    _Float16* q   = (_Float16*)ws;                       // 2 MB
    float* Ppre   = (float*)(ws + 2097152);              // 4 MB
    float* s      = (float*)(ws + 6291456);              // 32 KB
    _Float16* wT1 = (_Float16*)(ws + 6324224);           // 5 x 32 KB + g2h
    _Float16* wT2  = wT1 + 16384;
    _Float16* wTg  = wT2 + 16384;
    _Float16* wTq1 = wTg + 16384;
    _Float16* wTq2 = wTq1 + 16384;
    _Float16* g2h  = wTq2 + 16384;
    float* out = (float*)d_out;

    hipLaunchKernelGGL(prep_w, dim3(128), dim3(128), 0, stream,
                       nw1, nw2, gw1, gw2, qw1, qw2, wT1, wT2, wTg, wTq1, wTq2, g2h);
    hipLaunchKernelGGL(q_kernel, dim3(NB / 128), dim3(512), 0, stream,
                       u, wTq1, wTq2, qb1, qb2, q, Ppre, s);
    hipLaunchKernelGGL(hg_kernel, dim3((NN + 63) / 64), dim3(256), 0, stream,
                       x, batch, q, wT1, wT2, wTg, g2h, nb1, nb2, gb1, gb2, Ppre, s);
    hipLaunchKernelGGL(fin_kernel, dim3(NB / 128), dim3(512), 0, stream,
                       Ppre, s, wT2, nb2, out);
}